// Round 2
// baseline (824.161 us; speedup 1.0000x reference)
//
#include <hip/hip_runtime.h>
#include <hip/hip_bf16.h>
#include <math.h>

// ---------------- static geometry ----------------
#define R_TOTAL 100352   // B*N*S rows
#define CDIM    256
#define NWIN    2048     // B*N
#define NHEAD   8
#define HD      32
#define SW      49       // window tokens

typedef short s8v  __attribute__((ext_vector_type(8)));   // 8 bf16 (4 VGPR)
typedef float f32x4 __attribute__((ext_vector_type(4)));  // MFMA acc

// bf16 <-> f32 helpers on raw ushort storage
__device__ __forceinline__ unsigned short f2bf(float f) {
    __hip_bfloat16 h = __float2bfloat16(f);
    return *reinterpret_cast<unsigned short*>(&h);
}
__device__ __forceinline__ float bf2f(unsigned short u) {
    __hip_bfloat16 h;
    *reinterpret_cast<unsigned short*>(&h) = u;
    return __bfloat162float(h);
}

// async global->LDS, 16B per lane (lds dest = wave-uniform base + lane*16)
__device__ __forceinline__ void gload_lds16(const void* g, void* lds) {
    __builtin_amdgcn_global_load_lds(
        (const __attribute__((address_space(1))) void*)g,
        (__attribute__((address_space(3))) void*)lds, 16, 0, 0);
}

// ---------------- f32 -> bf16 convert (weights) ----------------
__global__ void cvt_f32_bf16(const float* __restrict__ in,
                             unsigned short* __restrict__ out, int n4) {
    int i = blockIdx.x * blockDim.x + threadIdx.x;
    if (i < n4) {
        float4 v = ((const float4*)in)[i];
        unsigned short o[4] = {f2bf(v.x), f2bf(v.y), f2bf(v.z), f2bf(v.w)};
        ((uint2*)out)[i] = *(uint2*)o;
    }
}

// ---------------- LayerNorm (C=256) -> bf16, one wave per row ----------------
__global__ __launch_bounds__(256)
void ln_rows(const float* __restrict__ in, const float* __restrict__ g,
             const float* __restrict__ b, unsigned short* __restrict__ out,
             int rows) {
    int wid = threadIdx.x >> 6, lane = threadIdx.x & 63;
    int row = blockIdx.x * 4 + wid;
    if (row >= rows) return;
    const float4 v = *(const float4*)(in + (size_t)row * CDIM + lane * 4);
    float s = v.x + v.y + v.z + v.w;
#pragma unroll
    for (int t = 1; t < 64; t <<= 1) s += __shfl_xor(s, t);
    float mean = s * (1.0f / 256.0f);
    float dx = v.x - mean, dy = v.y - mean, dz = v.z - mean, dw = v.w - mean;
    float q = dx * dx + dy * dy + dz * dz + dw * dw;
#pragma unroll
    for (int t = 1; t < 64; t <<= 1) q += __shfl_xor(q, t);
    float r = rsqrtf(q * (1.0f / 256.0f) + 1e-5f);
    const float4 gg = *(const float4*)(g + lane * 4);
    const float4 bb = *(const float4*)(b + lane * 4);
    unsigned short o[4] = {f2bf(dx * r * gg.x + bb.x), f2bf(dy * r * gg.y + bb.y),
                           f2bf(dz * r * gg.z + bb.z), f2bf(dw * r * gg.w + bb.w)};
    *(uint2*)(out + (size_t)row * CDIM + lane * 4) = *(uint2*)o;
}

// ---------------- bf16 NT GEMM: C[m][n] = sum_k A[m][k]*B[n][k] ----------------
// 128x128 tile, BK=32, 4 waves (2x2), each wave 64x64 via 4x4 16x16x32 MFMA.
// EPI: 0 = QKV scatter->bf16, 1 = proj(+bias+resid)->f32, 2 = mlp1(+bias,gelu)->bf16,
//      3 = mlp2(+bias+resid)->f32
template <int EPI>
__global__ __launch_bounds__(256)
void gemm_nt(const unsigned short* __restrict__ A, const unsigned short* __restrict__ B,
             const float* __restrict__ bias, const float* __restrict__ resid,
             void* __restrict__ outp, int M, int N, int K) {
    constexpr int BM = 128, BN = 128, BK = 32;
    __shared__ unsigned short As[BM][BK];   // 8 KiB
    __shared__ unsigned short Bs[BN][BK];   // 8 KiB

    const int tiles_n = N / BN;
    const int bm = blockIdx.x / tiles_n;
    const int bn = blockIdx.x % tiles_n;
    const int tid = threadIdx.x;
    const int wid = tid >> 6;
    const int lane = tid & 63;
    const int wr = wid >> 1, wc = wid & 1;
    const int fr = lane & 15;        // fragment row/col within 16-tile
    const int kc = lane >> 4;        // k-chunk 0..3 (8 elems each)

    f32x4 acc[4][4] = {};

    // staging: thread t covers bytes [t*16, t*16+16) of the 8 KiB tile, 2 issues
    const int srow = wid * 16 + (lane >> 2);   // tile row for issue 0
    const int scol = (lane & 3) * 8;           // element col
    const unsigned short* Abase = A + (size_t)(bm * BM) * K + scol;
    const unsigned short* Bbase = B + (size_t)(bn * BN) * K + scol;
    char* AsB = (char*)&As[0][0];
    char* BsB = (char*)&Bs[0][0];
    const int lbase = wid * 1024;

    for (int kt = 0; kt < K; kt += BK) {
        gload_lds16(Abase + (size_t)srow * K + kt,        AsB + lbase);
        gload_lds16(Abase + (size_t)(srow + 64) * K + kt, AsB + 4096 + lbase);
        gload_lds16(Bbase + (size_t)srow * K + kt,        BsB + lbase);
        gload_lds16(Bbase + (size_t)(srow + 64) * K + kt, BsB + 4096 + lbase);
        __syncthreads();   // drains vmcnt before barrier
        s8v af[4], bfr[4];
#pragma unroll
        for (int i = 0; i < 4; ++i) af[i]  = *(const s8v*)&As[wr * 64 + i * 16 + fr][kc * 8];
#pragma unroll
        for (int j = 0; j < 4; ++j) bfr[j] = *(const s8v*)&Bs[wc * 64 + j * 16 + fr][kc * 8];
#pragma unroll
        for (int i = 0; i < 4; ++i)
#pragma unroll
            for (int j = 0; j < 4; ++j)
                acc[i][j] = __builtin_amdgcn_mfma_f32_16x16x32_bf16(af[i], bfr[j], acc[i][j], 0, 0, 0);
        __syncthreads();
    }

    // epilogue: D layout col = lane&15, row = (lane>>4)*4 + v  [verified m89/m91]
    const int m0 = bm * BM + wr * 64;
    const int n0 = bn * BN + wc * 64;
#pragma unroll
    for (int i = 0; i < 4; ++i) {
#pragma unroll
        for (int j = 0; j < 4; ++j) {
#pragma unroll
            for (int v = 0; v < 4; ++v) {
                const int m = m0 + i * 16 + kc * 4 + v;
                const int n = n0 + j * 16 + fr;
                float val = acc[i][j][v] + bias[n];
                if constexpr (EPI == 0) {
                    // scatter qkv: n -> (part, head, d); m -> (window, s)
                    const int part = n >> 8;
                    const int c = n & 255;
                    const int head = c >> 5;
                    const int dd = c & 31;
                    const int win = m / SW;
                    const int s = m - win * SW;
                    ((unsigned short*)outp)[(size_t)part * ((size_t)NWIN * NHEAD * SW * HD)
                        + (((size_t)(win * NHEAD + head) * SW + s) * HD) + dd] = f2bf(val);
                } else if constexpr (EPI == 1) {
                    ((float*)outp)[(size_t)m * CDIM + n] = val + resid[(size_t)m * CDIM + n];
                } else if constexpr (EPI == 2) {
                    float gv = 0.5f * val * (1.0f + erff(val * 0.70710678118654752f));
                    ((unsigned short*)outp)[(size_t)m * 1024 + n] = f2bf(gv);
                } else {
                    ((float*)outp)[(size_t)m * CDIM + n] = val + resid[(size_t)m * CDIM + n];
                }
            }
        }
    }
}

// ---------------- fused window attention: one wave per (window, head) ----------------
__global__ __launch_bounds__(64)
void attn_win(const unsigned short* __restrict__ qkv,  // [3][NWIN*NH][49][32] bf16
              const float* __restrict__ btab,          // [169][8]
              unsigned short* __restrict__ outp)       // [R][256] bf16 (B,N,S,C)
{
    __shared__ unsigned short Qs[64][40];   // padded: 80B rows, 16B aligned
    __shared__ unsigned short Ks[64][40];
    __shared__ unsigned short Vt[32][72];   // V transposed: [d][j]
    __shared__ unsigned short Ps[64][72];   // probabilities bf16

    const int wh = blockIdx.x;
    const int win = wh >> 3;
    const int head = wh & 7;
    const int lane = threadIdx.x;
    const size_t s3 = (size_t)NWIN * NHEAD * SW * HD;
    const size_t base = (size_t)wh * (SW * HD);

    // ---- load Q,K rows; V transposed; zero pad rows 49..63 ----
    {
        const int r = lane;
        if (r < SW) {
            const int4* q4 = (const int4*)(qkv + base + r * HD);
            const int4* k4 = (const int4*)(qkv + s3 + base + r * HD);
            const int4* v4 = (const int4*)(qkv + 2 * s3 + base + r * HD);
            int4 vt[4];
#pragma unroll
            for (int c = 0; c < 4; ++c) {
                *(int4*)&Qs[r][c * 8] = q4[c];
                *(int4*)&Ks[r][c * 8] = k4[c];
                vt[c] = v4[c];
            }
            const unsigned short* vr = (const unsigned short*)vt;
#pragma unroll
            for (int d = 0; d < 32; ++d) Vt[d][r] = vr[d];
        } else {
            const int4 z = make_int4(0, 0, 0, 0);
#pragma unroll
            for (int c = 0; c < 4; ++c) {
                *(int4*)&Qs[r][c * 8] = z;
                *(int4*)&Ks[r][c * 8] = z;
            }
#pragma unroll
            for (int d = 0; d < 32; ++d) Vt[d][r] = 0;
        }
    }
    __syncthreads();

    const int fr = lane & 15, kc = lane >> 4;

    // ---- QK^T (64x64, K=32): NT form, 16 MFMA ----
    f32x4 sc[4][4] = {};
    {
        s8v qa[4], kb[4];
#pragma unroll
        for (int i = 0; i < 4; ++i) qa[i] = *(const s8v*)&Qs[i * 16 + fr][kc * 8];
#pragma unroll
        for (int j = 0; j < 4; ++j) kb[j] = *(const s8v*)&Ks[j * 16 + fr][kc * 8];
#pragma unroll
        for (int i = 0; i < 4; ++i)
#pragma unroll
            for (int j = 0; j < 4; ++j)
                sc[i][j] = __builtin_amdgcn_mfma_f32_16x16x32_bf16(qa[i], kb[j], sc[i][j], 0, 0, 0);
    }

    // ---- scale + rel-pos bias + shift mask + row softmax ----
    const float scale = 0.17677669529663687f;   // 32^-0.5
    const int nwin = win & 255;
    const bool lastrow = ((nwin >> 4) == 15);
    const bool lastcol = ((nwin & 15) == 15);

#pragma unroll
    for (int ti = 0; ti < 4; ++ti) {
#pragma unroll
        for (int v = 0; v < 4; ++v) {
            const int i = ti * 16 + kc * 4 + v;
            const int ih = i / 7, iw = i % 7;
            float vals[4];
#pragma unroll
            for (int tj = 0; tj < 4; ++tj) {
                const int j = tj * 16 + fr;
                float s;
                if (i < SW && j < SW) {
                    const int jh = j / 7, jw = j % 7;
                    const float bv = btab[((ih - jh + 6) * 13 + (iw - jw + 6)) * NHEAD + head];
                    s = sc[ti][tj][v] * scale + bv;
                    const bool msk = (lastrow && ((ih < 4) != (jh < 4))) ||
                                     (lastcol && ((iw < 4) != (jw < 4)));
                    if (msk) s = -1e30f;
                } else {
                    s = -1e30f;
                }
                vals[tj] = s;
            }
            float mx = fmaxf(fmaxf(vals[0], vals[1]), fmaxf(vals[2], vals[3]));
#pragma unroll
            for (int t = 1; t < 16; t <<= 1) mx = fmaxf(mx, __shfl_xor(mx, t));
            float e[4], sum = 0.0f;
#pragma unroll
            for (int tj = 0; tj < 4; ++tj) { e[tj] = __expf(vals[tj] - mx); sum += e[tj]; }
#pragma unroll
            for (int t = 1; t < 16; t <<= 1) sum += __shfl_xor(sum, t);
            const float inv = 1.0f / sum;
#pragma unroll
            for (int tj = 0; tj < 4; ++tj)
                Ps[i][tj * 16 + fr] = f2bf(e[tj] * inv);
        }
    }
    __syncthreads();

    // ---- PV (64x32, K=64): A=Ps rows, B=Vt rows (NT), 16 MFMA ----
    f32x4 oa[4][2] = {};
#pragma unroll
    for (int ks = 0; ks < 2; ++ks) {
        s8v pa[4], vb[2];
#pragma unroll
        for (int ti = 0; ti < 4; ++ti) pa[ti] = *(const s8v*)&Ps[ti * 16 + fr][ks * 32 + kc * 8];
#pragma unroll
        for (int tj = 0; tj < 2; ++tj) vb[tj] = *(const s8v*)&Vt[tj * 16 + fr][ks * 32 + kc * 8];
#pragma unroll
        for (int ti = 0; ti < 4; ++ti)
#pragma unroll
            for (int tj = 0; tj < 2; ++tj)
                oa[ti][tj] = __builtin_amdgcn_mfma_f32_16x16x32_bf16(pa[ti], vb[tj], oa[ti][tj], 0, 0, 0);
    }

    // ---- write out rows i<49 into (B,N,S,C) bf16 ----
#pragma unroll
    for (int ti = 0; ti < 4; ++ti)
#pragma unroll
        for (int tj = 0; tj < 2; ++tj)
#pragma unroll
            for (int v = 0; v < 4; ++v) {
                const int i = ti * 16 + kc * 4 + v;
                if (i < SW) {
                    const int d = tj * 16 + fr;
                    outp[((size_t)win * SW + i) * CDIM + head * HD + d] = f2bf(oa[ti][tj][v]);
                }
            }
}

// ---------------- host orchestration ----------------
extern "C" void kernel_launch(void* const* d_in, const int* in_sizes, int n_in,
                              void* d_out, int out_size, void* d_ws, size_t ws_size,
                              hipStream_t stream) {
    const float* x       = (const float*)d_in[0];
    // d_in[1] = reshape (int64) - unused, geometry is static
    const float* n1g     = (const float*)d_in[2];
    const float* n1b     = (const float*)d_in[3];
    const float* qkv_w   = (const float*)d_in[4];
    const float* qkv_b   = (const float*)d_in[5];
    const float* proj_w  = (const float*)d_in[6];
    const float* proj_b  = (const float*)d_in[7];
    const float* n2g     = (const float*)d_in[8];
    const float* n2b     = (const float*)d_in[9];
    const float* mlp_w1  = (const float*)d_in[10];
    const float* mlp_b1  = (const float*)d_in[11];
    const float* mlp_w2  = (const float*)d_in[12];
    const float* mlp_b2  = (const float*)d_in[13];
    const float* btab    = (const float*)d_in[14];

    const int R = R_TOTAL;

    // workspace layout (bytes); hid reuses qkv+attno (dead by then), h2 reuses h
    char* w = (char*)d_ws;
    unsigned short* wqkv  = (unsigned short*)w; w += (size_t)768 * 256 * 2;
    unsigned short* wproj = (unsigned short*)w; w += (size_t)256 * 256 * 2;
    unsigned short* wm1   = (unsigned short*)w; w += (size_t)1024 * 256 * 2;
    unsigned short* wm2   = (unsigned short*)w; w += (size_t)256 * 1024 * 2;
    unsigned short* hbuf  = (unsigned short*)w; w += (size_t)R * CDIM * 2;
    unsigned short* qkvb  = (unsigned short*)w;
    unsigned short* hid   = qkvb;               w += (size_t)3 * R * CDIM * 2;
    unsigned short* attno = (unsigned short*)w; w += (size_t)R * CDIM * 2;
    float*          x2    = (float*)w;          w += (size_t)R * CDIM * 4;
    unsigned short* h2    = hbuf;

    // weights -> bf16
    cvt_f32_bf16<<<192, 256, 0, stream>>>(qkv_w,  wqkv, 49152);
    cvt_f32_bf16<<<64,  256, 0, stream>>>(proj_w, wproj, 16384);
    cvt_f32_bf16<<<256, 256, 0, stream>>>(mlp_w1, wm1, 65536);
    cvt_f32_bf16<<<256, 256, 0, stream>>>(mlp_w2, wm2, 65536);

    // LN1 -> h (bf16)
    ln_rows<<<R / 4, 256, 0, stream>>>(x, n1g, n1b, hbuf, R);

    // QKV GEMM -> scattered qkv layout
    gemm_nt<0><<<784 * 6, 256, 0, stream>>>(hbuf, wqkv, qkv_b, nullptr, qkvb, R, 768, 256);

    // fused window attention
    attn_win<<<NWIN * NHEAD, 64, 0, stream>>>(qkvb, btab, attno);

    // proj GEMM + residual -> x2 (f32)
    gemm_nt<1><<<784 * 2, 256, 0, stream>>>(attno, wproj, proj_b, x, x2, R, 256, 256);

    // LN2 -> h2 (bf16)
    ln_rows<<<R / 4, 256, 0, stream>>>(x2, n2g, n2b, h2, R);

    // MLP1 + gelu -> hid (bf16)
    gemm_nt<2><<<784 * 8, 256, 0, stream>>>(h2, wm1, mlp_b1, nullptr, hid, R, 1024, 256);

    // MLP2 + residual -> d_out (f32)
    gemm_nt<3><<<784 * 2, 256, 0, stream>>>(hid, wm2, mlp_b2, x2, (float*)d_out, R, 256, 1024);
}

// Round 3
// 751.473 us; speedup vs baseline: 1.0967x; 1.0967x over previous
//
#include <hip/hip_runtime.h>
#include <hip/hip_bf16.h>
#include <math.h>

// ---------------- static geometry ----------------
#define R_TOTAL 100352   // B*N*S rows
#define CDIM    256
#define NWIN    2048     // B*N
#define NHEAD   8
#define HD      32
#define SW      49       // window tokens

typedef short s8v  __attribute__((ext_vector_type(8)));   // 8 bf16 (4 VGPR)
typedef float f32x4 __attribute__((ext_vector_type(4)));  // MFMA acc

// bf16 <-> f32 helpers on raw ushort storage
__device__ __forceinline__ unsigned short f2bf(float f) {
    __hip_bfloat16 h = __float2bfloat16(f);
    return *reinterpret_cast<unsigned short*>(&h);
}

// async global->LDS, 16B per lane (lds dest = wave-uniform base + lane*16)
__device__ __forceinline__ void gload_lds16(const void* g, void* lds) {
    __builtin_amdgcn_global_load_lds(
        (const __attribute__((address_space(1))) void*)g,
        (__attribute__((address_space(3))) void*)lds, 16, 0, 0);
}

// ---------------- f32 -> bf16 convert (weights) ----------------
__global__ void cvt_f32_bf16(const float* __restrict__ in,
                             unsigned short* __restrict__ out, int n4) {
    int i = blockIdx.x * blockDim.x + threadIdx.x;
    if (i < n4) {
        float4 v = ((const float4*)in)[i];
        unsigned short o[4] = {f2bf(v.x), f2bf(v.y), f2bf(v.z), f2bf(v.w)};
        ((uint2*)out)[i] = *(uint2*)o;
    }
}

// ---------------- LayerNorm (C=256) -> bf16, one wave per row ----------------
__global__ __launch_bounds__(256)
void ln_rows(const float* __restrict__ in, const float* __restrict__ g,
             const float* __restrict__ b, unsigned short* __restrict__ out,
             int rows) {
    int wid = threadIdx.x >> 6, lane = threadIdx.x & 63;
    int row = blockIdx.x * 4 + wid;
    if (row >= rows) return;
    const float4 v = *(const float4*)(in + (size_t)row * CDIM + lane * 4);
    float s = v.x + v.y + v.z + v.w;
#pragma unroll
    for (int t = 1; t < 64; t <<= 1) s += __shfl_xor(s, t);
    float mean = s * (1.0f / 256.0f);
    float dx = v.x - mean, dy = v.y - mean, dz = v.z - mean, dw = v.w - mean;
    float q = dx * dx + dy * dy + dz * dz + dw * dw;
#pragma unroll
    for (int t = 1; t < 64; t <<= 1) q += __shfl_xor(q, t);
    float r = rsqrtf(q * (1.0f / 256.0f) + 1e-5f);
    const float4 gg = *(const float4*)(g + lane * 4);
    const float4 bb = *(const float4*)(b + lane * 4);
    unsigned short o[4] = {f2bf(dx * r * gg.x + bb.x), f2bf(dy * r * gg.y + bb.y),
                           f2bf(dz * r * gg.z + bb.z), f2bf(dw * r * gg.w + bb.w)};
    *(uint2*)(out + (size_t)row * CDIM + lane * 4) = *(uint2*)o;
}

// ---------------- bf16 NT GEMM: C[m][n] = sum_k A[m][k]*B[n][k] ----------------
// 128x128 tile, BK=32, 4 waves (2x2), each wave 64x64 via 4x4 16x16x32 MFMA.
// EPI: 0 = QKV scatter->bf16, 1 = proj(+bias+resid)->f32, 2 = mlp1(+bias,gelu)->bf16,
//      3 = mlp2(+bias+resid)->f32
template <int EPI>
__global__ __launch_bounds__(256)
void gemm_nt(const unsigned short* __restrict__ A, const unsigned short* __restrict__ B,
             const float* __restrict__ bias, const float* __restrict__ resid,
             void* __restrict__ outp, int M, int N, int K) {
    constexpr int BM = 128, BN = 128, BK = 32;
    __shared__ unsigned short As[BM][BK];   // 8 KiB
    __shared__ unsigned short Bs[BN][BK];   // 8 KiB

    const int tiles_n = N / BN;
    const int bm = blockIdx.x / tiles_n;
    const int bn = blockIdx.x % tiles_n;
    const int tid = threadIdx.x;
    const int wid = tid >> 6;
    const int lane = tid & 63;
    const int wr = wid >> 1, wc = wid & 1;
    const int fr = lane & 15;        // fragment row/col within 16-tile
    const int kc = lane >> 4;        // k-chunk 0..3 (8 elems each)

    f32x4 acc[4][4] = {};

    // staging: thread t covers bytes [t*16, t*16+16) of the 8 KiB tile, 2 issues
    const int srow = wid * 16 + (lane >> 2);   // tile row for issue 0
    const int scol = (lane & 3) * 8;           // element col
    const unsigned short* Abase = A + (size_t)(bm * BM) * K + scol;
    const unsigned short* Bbase = B + (size_t)(bn * BN) * K + scol;
    char* AsB = (char*)&As[0][0];
    char* BsB = (char*)&Bs[0][0];
    const int lbase = wid * 1024;

    for (int kt = 0; kt < K; kt += BK) {
        gload_lds16(Abase + (size_t)srow * K + kt,        AsB + lbase);
        gload_lds16(Abase + (size_t)(srow + 64) * K + kt, AsB + 4096 + lbase);
        gload_lds16(Bbase + (size_t)srow * K + kt,        BsB + lbase);
        gload_lds16(Bbase + (size_t)(srow + 64) * K + kt, BsB + 4096 + lbase);
        __syncthreads();   // drains vmcnt before barrier
        s8v af[4], bfr[4];
#pragma unroll
        for (int i = 0; i < 4; ++i) af[i]  = *(const s8v*)&As[wr * 64 + i * 16 + fr][kc * 8];
#pragma unroll
        for (int j = 0; j < 4; ++j) bfr[j] = *(const s8v*)&Bs[wc * 64 + j * 16 + fr][kc * 8];
#pragma unroll
        for (int i = 0; i < 4; ++i)
#pragma unroll
            for (int j = 0; j < 4; ++j)
                acc[i][j] = __builtin_amdgcn_mfma_f32_16x16x32_bf16(af[i], bfr[j], acc[i][j], 0, 0, 0);
        __syncthreads();
    }

    // epilogue: D layout col = lane&15, row = (lane>>4)*4 + v  [verified m89/m91]
    const int m0 = bm * BM + wr * 64;
    const int n0 = bn * BN + wc * 64;
#pragma unroll
    for (int i = 0; i < 4; ++i) {
#pragma unroll
        for (int j = 0; j < 4; ++j) {
#pragma unroll
            for (int v = 0; v < 4; ++v) {
                const int m = m0 + i * 16 + kc * 4 + v;
                const int n = n0 + j * 16 + fr;
                float val = acc[i][j][v] + bias[n];
                if constexpr (EPI == 0) {
                    // scatter qkv: n -> (part, head, d); m -> (window, s)
                    const int part = n >> 8;
                    const int c = n & 255;
                    const int head = c >> 5;
                    const int dd = c & 31;
                    const int win = m / SW;
                    const int s = m - win * SW;
                    ((unsigned short*)outp)[(size_t)part * ((size_t)NWIN * NHEAD * SW * HD)
                        + (((size_t)(win * NHEAD + head) * SW + s) * HD) + dd] = f2bf(val);
                } else if constexpr (EPI == 1) {
                    ((float*)outp)[(size_t)m * CDIM + n] = val + resid[(size_t)m * CDIM + n];
                } else if constexpr (EPI == 2) {
                    float gv = 0.5f * val * (1.0f + erff(val * 0.70710678118654752f));
                    ((unsigned short*)outp)[(size_t)m * 1024 + n] = f2bf(gv);
                } else {
                    ((float*)outp)[(size_t)m * CDIM + n] = val + resid[(size_t)m * CDIM + n];
                }
            }
        }
    }
}

// ---------------- fused window attention: one wave per (window, head) ----------------
// LDS-slim version: Q/K MFMA fragments come straight from global (L2/L3-warm),
// bias column staged in LDS. 14.5 KiB/block -> ~11 blocks/CU (was 24 KiB -> 6).
__global__ __launch_bounds__(64)
void attn_win(const unsigned short* __restrict__ qkv,  // [3][NWIN*NH][49][32] bf16
              const float* __restrict__ btab,          // [169][8]
              unsigned short* __restrict__ outp)       // [R][256] bf16 (B,N,S,C)
{
    __shared__ unsigned short Vt[32][72];   // V transposed: [d][j], 4608 B
    __shared__ unsigned short Ps[64][72];   // probabilities bf16, 9216 B
    __shared__ float bcol[169];             // bias column for this head, 676 B

    const int wh = blockIdx.x;
    const int win = wh >> 3;
    const int head = wh & 7;
    const int lane = threadIdx.x;
    const size_t s3 = (size_t)NWIN * NHEAD * SW * HD;
    const size_t base = (size_t)wh * (SW * HD);

    // ---- bias column -> LDS ----
    for (int t = lane; t < 169; t += 64) bcol[t] = btab[t * NHEAD + head];

    // ---- V rows -> Vt transposed; zero pad cols 49..63 ----
    {
        const int r = lane;
        if (r < SW) {
            const int4* v4 = (const int4*)(qkv + 2 * s3 + base + (size_t)r * HD);
            int4 vt[4];
#pragma unroll
            for (int c = 0; c < 4; ++c) vt[c] = v4[c];
            const unsigned short* vr = (const unsigned short*)vt;
#pragma unroll
            for (int d = 0; d < 32; ++d) Vt[d][r] = vr[d];
        } else {
#pragma unroll
            for (int d = 0; d < 32; ++d) Vt[d][r] = 0;
        }
    }

    const int fr = lane & 15, kc = lane >> 4;

    // ---- Q,K fragments direct from global (rows>=49 read in-bounds garbage,
    //      masked below; last window's overrun stays inside the qkv buffer) ----
    s8v qa[4], kb[4];
    {
        const unsigned short* Qg = qkv + base;
        const unsigned short* Kg = qkv + s3 + base;
#pragma unroll
        for (int i = 0; i < 4; ++i)
            qa[i] = *(const s8v*)(Qg + (size_t)(i * 16 + fr) * HD + kc * 8);
#pragma unroll
        for (int j = 0; j < 4; ++j)
            kb[j] = *(const s8v*)(Kg + (size_t)(j * 16 + fr) * HD + kc * 8);
    }

    // ---- QK^T (64x64, K=32): NT form, 16 MFMA ----
    f32x4 sc[4][4] = {};
#pragma unroll
    for (int i = 0; i < 4; ++i)
#pragma unroll
        for (int j = 0; j < 4; ++j)
            sc[i][j] = __builtin_amdgcn_mfma_f32_16x16x32_bf16(qa[i], kb[j], sc[i][j], 0, 0, 0);

    __syncthreads();   // Vt + bcol visible (single wave: cheap)

    // ---- scale + rel-pos bias + shift mask + row softmax ----
    const float scale = 0.17677669529663687f;   // 32^-0.5
    const int nwin = win & 255;
    const bool lastrow = ((nwin >> 4) == 15);
    const bool lastcol = ((nwin & 15) == 15);

    // hoisted per-lane j-side quantities
    int cj[4];
    bool jh4[4], jw4[4], jvalid[4];
#pragma unroll
    for (int tj = 0; tj < 4; ++tj) {
        const int j = tj * 16 + fr;
        const int jh = j / 7, jw = j - jh * 7;
        jvalid[tj] = (j < SW);
        cj[tj] = jh * 13 + jw;
        jh4[tj] = (jh < 4);
        jw4[tj] = (jw < 4);
    }

#pragma unroll
    for (int ti = 0; ti < 4; ++ti) {
#pragma unroll
        for (int v = 0; v < 4; ++v) {
            const int i = ti * 16 + kc * 4 + v;
            const int ih = i / 7, iw = i - ih * 7;
            const bool ivalid = (i < SW);
            const int ci = ih * 13 + iw;
            const bool ih4 = (ih < 4), iw4 = (iw < 4);
            float vals[4];
#pragma unroll
            for (int tj = 0; tj < 4; ++tj) {
                const bool ok = ivalid && jvalid[tj];
                const int bidx = ok ? (ci - cj[tj] + 84) : 0;  // clamp: no OOB LDS
                const float bv = bcol[bidx];
                const bool msk = (lastrow && (ih4 != jh4[tj])) ||
                                 (lastcol && (iw4 != jw4[tj]));
                const float s = sc[ti][tj][v] * scale + bv;
                vals[tj] = (ok && !msk) ? s : -1e30f;
            }
            float mx = fmaxf(fmaxf(vals[0], vals[1]), fmaxf(vals[2], vals[3]));
#pragma unroll
            for (int t = 1; t < 16; t <<= 1) mx = fmaxf(mx, __shfl_xor(mx, t));
            float e[4], sum = 0.0f;
#pragma unroll
            for (int tj = 0; tj < 4; ++tj) { e[tj] = __expf(vals[tj] - mx); sum += e[tj]; }
#pragma unroll
            for (int t = 1; t < 16; t <<= 1) sum += __shfl_xor(sum, t);
            const float inv = 1.0f / sum;
#pragma unroll
            for (int tj = 0; tj < 4; ++tj)
                Ps[i][tj * 16 + fr] = f2bf(e[tj] * inv);   // exact zeros for j>=49
        }
    }
    __syncthreads();

    // ---- PV (64x32, K=64): A=Ps rows, B=Vt rows (NT), 16 MFMA ----
    f32x4 oa[4][2] = {};
#pragma unroll
    for (int ks = 0; ks < 2; ++ks) {
        s8v pa[4], vb[2];
#pragma unroll
        for (int ti = 0; ti < 4; ++ti) pa[ti] = *(const s8v*)&Ps[ti * 16 + fr][ks * 32 + kc * 8];
#pragma unroll
        for (int tj = 0; tj < 2; ++tj) vb[tj] = *(const s8v*)&Vt[tj * 16 + fr][ks * 32 + kc * 8];
#pragma unroll
        for (int ti = 0; ti < 4; ++ti)
#pragma unroll
            for (int tj = 0; tj < 2; ++tj)
                oa[ti][tj] = __builtin_amdgcn_mfma_f32_16x16x32_bf16(pa[ti], vb[tj], oa[ti][tj], 0, 0, 0);
    }

    // ---- write out rows i<49 into (B,N,S,C) bf16 ----
#pragma unroll
    for (int ti = 0; ti < 4; ++ti)
#pragma unroll
        for (int tj = 0; tj < 2; ++tj)
#pragma unroll
            for (int v = 0; v < 4; ++v) {
                const int i = ti * 16 + kc * 4 + v;
                if (i < SW) {
                    const int d = tj * 16 + fr;
                    outp[((size_t)win * SW + i) * CDIM + head * HD + d] = f2bf(oa[ti][tj][v]);
                }
            }
}

// ---------------- host orchestration ----------------
extern "C" void kernel_launch(void* const* d_in, const int* in_sizes, int n_in,
                              void* d_out, int out_size, void* d_ws, size_t ws_size,
                              hipStream_t stream) {
    const float* x       = (const float*)d_in[0];
    // d_in[1] = reshape (int64) - unused, geometry is static
    const float* n1g     = (const float*)d_in[2];
    const float* n1b     = (const float*)d_in[3];
    const float* qkv_w   = (const float*)d_in[4];
    const float* qkv_b   = (const float*)d_in[5];
    const float* proj_w  = (const float*)d_in[6];
    const float* proj_b  = (const float*)d_in[7];
    const float* n2g     = (const float*)d_in[8];
    const float* n2b     = (const float*)d_in[9];
    const float* mlp_w1  = (const float*)d_in[10];
    const float* mlp_b1  = (const float*)d_in[11];
    const float* mlp_w2  = (const float*)d_in[12];
    const float* mlp_b2  = (const float*)d_in[13];
    const float* btab    = (const float*)d_in[14];

    const int R = R_TOTAL;

    // workspace layout (bytes); hid reuses qkv+attno (dead by then), h2 reuses h
    char* w = (char*)d_ws;
    unsigned short* wqkv  = (unsigned short*)w; w += (size_t)768 * 256 * 2;
    unsigned short* wproj = (unsigned short*)w; w += (size_t)256 * 256 * 2;
    unsigned short* wm1   = (unsigned short*)w; w += (size_t)1024 * 256 * 2;
    unsigned short* wm2   = (unsigned short*)w; w += (size_t)256 * 1024 * 2;
    unsigned short* hbuf  = (unsigned short*)w; w += (size_t)R * CDIM * 2;
    unsigned short* qkvb  = (unsigned short*)w;
    unsigned short* hid   = qkvb;               w += (size_t)3 * R * CDIM * 2;
    unsigned short* attno = (unsigned short*)w; w += (size_t)R * CDIM * 2;
    float*          x2    = (float*)w;          w += (size_t)R * CDIM * 4;
    unsigned short* h2    = hbuf;

    // weights -> bf16
    cvt_f32_bf16<<<192, 256, 0, stream>>>(qkv_w,  wqkv, 49152);
    cvt_f32_bf16<<<64,  256, 0, stream>>>(proj_w, wproj, 16384);
    cvt_f32_bf16<<<256, 256, 0, stream>>>(mlp_w1, wm1, 65536);
    cvt_f32_bf16<<<256, 256, 0, stream>>>(mlp_w2, wm2, 65536);

    // LN1 -> h (bf16)
    ln_rows<<<R / 4, 256, 0, stream>>>(x, n1g, n1b, hbuf, R);

    // QKV GEMM -> scattered qkv layout
    gemm_nt<0><<<784 * 6, 256, 0, stream>>>(hbuf, wqkv, qkv_b, nullptr, qkvb, R, 768, 256);

    // fused window attention
    attn_win<<<NWIN * NHEAD, 64, 0, stream>>>(qkvb, btab, attno);

    // proj GEMM + residual -> x2 (f32)
    gemm_nt<1><<<784 * 2, 256, 0, stream>>>(attno, wproj, proj_b, x, x2, R, 256, 256);

    // LN2 -> h2 (bf16)
    ln_rows<<<R / 4, 256, 0, stream>>>(x2, n2g, n2b, h2, R);

    // MLP1 + gelu -> hid (bf16)
    gemm_nt<2><<<784 * 8, 256, 0, stream>>>(h2, wm1, mlp_b1, nullptr, hid, R, 1024, 256);

    // MLP2 + residual -> d_out (f32)
    gemm_nt<3><<<784 * 2, 256, 0, stream>>>(hid, wm2, mlp_b2, x2, (float*)d_out, R, 256, 1024);
}

// Round 4
// 663.682 us; speedup vs baseline: 1.2418x; 1.1323x over previous
//
#include <hip/hip_runtime.h>
#include <hip/hip_bf16.h>
#include <math.h>

// ---------------- static geometry ----------------
#define R_TOTAL 100352   // B*N*S rows
#define CDIM    256
#define NWIN    2048     // B*N
#define NHEAD   8
#define HD      32
#define SW      49       // window tokens

typedef short s8v  __attribute__((ext_vector_type(8)));   // 8 bf16 (4 VGPR)
typedef float f32x4 __attribute__((ext_vector_type(4)));  // MFMA acc

// bf16 <-> f32 helpers on raw ushort storage
__device__ __forceinline__ unsigned short f2bf(float f) {
    __hip_bfloat16 h = __float2bfloat16(f);
    return *reinterpret_cast<unsigned short*>(&h);
}

// async global->LDS, 16B per lane (lds dest = wave-uniform base + lane*16)
__device__ __forceinline__ void gload_lds16(const void* g, void* lds) {
    __builtin_amdgcn_global_load_lds(
        (const __attribute__((address_space(1))) void*)g,
        (__attribute__((address_space(3))) void*)lds, 16, 0, 0);
}

// ---------------- f32 -> bf16 convert (weights) ----------------
__global__ void cvt_f32_bf16(const float* __restrict__ in,
                             unsigned short* __restrict__ out, int n4) {
    int i = blockIdx.x * blockDim.x + threadIdx.x;
    if (i < n4) {
        float4 v = ((const float4*)in)[i];
        unsigned short o[4] = {f2bf(v.x), f2bf(v.y), f2bf(v.z), f2bf(v.w)};
        ((uint2*)out)[i] = *(uint2*)o;
    }
}

// ---------------- LayerNorm (C=256) -> bf16, one wave per row ----------------
__global__ __launch_bounds__(256)
void ln_rows(const float* __restrict__ in, const float* __restrict__ g,
             const float* __restrict__ b, unsigned short* __restrict__ out,
             int rows) {
    int wid = threadIdx.x >> 6, lane = threadIdx.x & 63;
    int row = blockIdx.x * 4 + wid;
    if (row >= rows) return;
    const float4 v = *(const float4*)(in + (size_t)row * CDIM + lane * 4);
    float s = v.x + v.y + v.z + v.w;
#pragma unroll
    for (int t = 1; t < 64; t <<= 1) s += __shfl_xor(s, t);
    float mean = s * (1.0f / 256.0f);
    float dx = v.x - mean, dy = v.y - mean, dz = v.z - mean, dw = v.w - mean;
    float q = dx * dx + dy * dy + dz * dz + dw * dw;
#pragma unroll
    for (int t = 1; t < 64; t <<= 1) q += __shfl_xor(q, t);
    float r = rsqrtf(q * (1.0f / 256.0f) + 1e-5f);
    const float4 gg = *(const float4*)(g + lane * 4);
    const float4 bb = *(const float4*)(b + lane * 4);
    unsigned short o[4] = {f2bf(dx * r * gg.x + bb.x), f2bf(dy * r * gg.y + bb.y),
                           f2bf(dz * r * gg.z + bb.z), f2bf(dw * r * gg.w + bb.w)};
    *(uint2*)(out + (size_t)row * CDIM + lane * 4) = *(uint2*)o;
}

// ---------------- bf16 NT GEMM: C[m][n] = sum_k A[m][k]*B[n][k] ----------------
// 128x128 tile, BK=32, 4 waves (2x2), each wave 64x64 via 4x4 16x16x32 MFMA.
// 2-phase double-buffered LDS (T3 minimum recipe): stage(next) issued before
// compute(cur), ONE barrier per K-step. XCD-chunked block swizzle (T1).
// EPI: 0 = QKV scatter->bf16, 1 = proj(+bias+resid)->f32, 2 = mlp1(+bias,gelu)->bf16,
//      3 = mlp2(+bias+resid)->f32
template <int EPI>
__global__ __launch_bounds__(256, 4)
void gemm_nt(const unsigned short* __restrict__ A, const unsigned short* __restrict__ B,
             const float* __restrict__ bias, const float* __restrict__ resid,
             void* __restrict__ outp, int M, int N, int K) {
    constexpr int BM = 128, BN = 128, BK = 32;
    __shared__ unsigned short As[2][BM][BK];   // 16 KiB (double-buffered)
    __shared__ unsigned short Bs[2][BN][BK];   // 16 KiB

    // T1: XCD-chunked swizzle (all grids are multiples of 8)
    const int nwg = gridDim.x;
    const int cpx = nwg >> 3;
    const int bid = blockIdx.x;
    const int swz = (bid & 7) * cpx + (bid >> 3);

    const int tiles_n = N / BN;
    const int bm = swz / tiles_n;
    const int bn = swz % tiles_n;
    const int tid = threadIdx.x;
    const int wid = tid >> 6;
    const int lane = tid & 63;
    const int wr = wid >> 1, wc = wid & 1;
    const int fr = lane & 15;        // fragment row/col within 16-tile
    const int kc = lane >> 4;        // k-chunk 0..3 (8 elems each)

    f32x4 acc[4][4] = {};

    // staging: thread t covers bytes [t*16, t*16+16) of the 8 KiB half-tile, 2 issues
    const int srow = wid * 16 + (lane >> 2);   // tile row for issue 0
    const int scol = (lane & 3) * 8;           // element col
    const unsigned short* Abase = A + (size_t)(bm * BM) * K + scol;
    const unsigned short* Bbase = B + (size_t)(bn * BN) * K + scol;
    char* AsB = (char*)&As[0][0][0];
    char* BsB = (char*)&Bs[0][0][0];
    const int lbase = wid * 1024;

    auto stage = [&](int buf, int kt) {
        char* Ad = AsB + buf * 8192 + lbase;
        char* Bd = BsB + buf * 8192 + lbase;
        gload_lds16(Abase + (size_t)srow * K + kt,        Ad);
        gload_lds16(Abase + (size_t)(srow + 64) * K + kt, Ad + 4096);
        gload_lds16(Bbase + (size_t)srow * K + kt,        Bd);
        gload_lds16(Bbase + (size_t)(srow + 64) * K + kt, Bd + 4096);
    };
    auto compute = [&](int buf) {
        s8v af[4], bfr[4];
#pragma unroll
        for (int i = 0; i < 4; ++i) af[i]  = *(const s8v*)&As[buf][wr * 64 + i * 16 + fr][kc * 8];
#pragma unroll
        for (int j = 0; j < 4; ++j) bfr[j] = *(const s8v*)&Bs[buf][wc * 64 + j * 16 + fr][kc * 8];
#pragma unroll
        for (int i = 0; i < 4; ++i)
#pragma unroll
            for (int j = 0; j < 4; ++j)
                acc[i][j] = __builtin_amdgcn_mfma_f32_16x16x32_bf16(af[i], bfr[j], acc[i][j], 0, 0, 0);
    };

    // prologue: stage tile 0, drain, then 2-phase loop (one barrier per K-step)
    stage(0, 0);
    __syncthreads();
    int cur = 0;
    for (int kt = BK; kt < K; kt += BK) {
        stage(cur ^ 1, kt);    // issue next-tile loads (fly during compute)
        compute(cur);          // ds_read + MFMA (compiler-managed lgkmcnt)
        __syncthreads();       // drains vmcnt -> next buffer ready
        cur ^= 1;
    }
    compute(cur);              // epilogue tile, no prefetch

    // epilogue: D layout col = lane&15, row = (lane>>4)*4 + v  [verified m89/m91]
    const int m0 = bm * BM + wr * 64;
    const int n0 = bn * BN + wc * 64;
#pragma unroll
    for (int i = 0; i < 4; ++i) {
#pragma unroll
        for (int j = 0; j < 4; ++j) {
#pragma unroll
            for (int v = 0; v < 4; ++v) {
                const int m = m0 + i * 16 + kc * 4 + v;
                const int n = n0 + j * 16 + fr;
                float val = acc[i][j][v] + bias[n];
                if constexpr (EPI == 0) {
                    // scatter qkv: n -> (part, head, d); m -> (window, s)
                    const int part = n >> 8;
                    const int c = n & 255;
                    const int head = c >> 5;
                    const int dd = c & 31;
                    const int win = m / SW;
                    const int s = m - win * SW;
                    ((unsigned short*)outp)[(size_t)part * ((size_t)NWIN * NHEAD * SW * HD)
                        + (((size_t)(win * NHEAD + head) * SW + s) * HD) + dd] = f2bf(val);
                } else if constexpr (EPI == 1) {
                    ((float*)outp)[(size_t)m * CDIM + n] = val + resid[(size_t)m * CDIM + n];
                } else if constexpr (EPI == 2) {
                    float gv = 0.5f * val * (1.0f + erff(val * 0.70710678118654752f));
                    ((unsigned short*)outp)[(size_t)m * 1024 + n] = f2bf(gv);
                } else {
                    ((float*)outp)[(size_t)m * CDIM + n] = val + resid[(size_t)m * CDIM + n];
                }
            }
        }
    }
}

// ---------------- fused window attention: one wave per (window, head) ----------------
// LDS-slim version: Q/K MFMA fragments come straight from global (L2/L3-warm),
// bias column staged in LDS. 14.5 KiB/block -> ~11 blocks/CU.
__global__ __launch_bounds__(64)
void attn_win(const unsigned short* __restrict__ qkv,  // [3][NWIN*NH][49][32] bf16
              const float* __restrict__ btab,          // [169][8]
              unsigned short* __restrict__ outp)       // [R][256] bf16 (B,N,S,C)
{
    __shared__ unsigned short Vt[32][72];   // V transposed: [d][j], 4608 B
    __shared__ unsigned short Ps[64][72];   // probabilities bf16, 9216 B
    __shared__ float bcol[169];             // bias column for this head, 676 B

    const int wh = blockIdx.x;
    const int win = wh >> 3;
    const int head = wh & 7;
    const int lane = threadIdx.x;
    const size_t s3 = (size_t)NWIN * NHEAD * SW * HD;
    const size_t base = (size_t)wh * (SW * HD);

    // ---- bias column -> LDS ----
    for (int t = lane; t < 169; t += 64) bcol[t] = btab[t * NHEAD + head];

    // ---- V rows -> Vt transposed; zero pad cols 49..63 ----
    {
        const int r = lane;
        if (r < SW) {
            const int4* v4 = (const int4*)(qkv + 2 * s3 + base + (size_t)r * HD);
            int4 vt[4];
#pragma unroll
            for (int c = 0; c < 4; ++c) vt[c] = v4[c];
            const unsigned short* vr = (const unsigned short*)vt;
#pragma unroll
            for (int d = 0; d < 32; ++d) Vt[d][r] = vr[d];
        } else {
#pragma unroll
            for (int d = 0; d < 32; ++d) Vt[d][r] = 0;
        }
    }

    const int fr = lane & 15, kc = lane >> 4;

    // ---- Q,K fragments direct from global (rows>=49 read in-bounds garbage,
    //      masked below; last window's overrun stays inside the qkv buffer) ----
    s8v qa[4], kb[4];
    {
        const unsigned short* Qg = qkv + base;
        const unsigned short* Kg = qkv + s3 + base;
#pragma unroll
        for (int i = 0; i < 4; ++i)
            qa[i] = *(const s8v*)(Qg + (size_t)(i * 16 + fr) * HD + kc * 8);
#pragma unroll
        for (int j = 0; j < 4; ++j)
            kb[j] = *(const s8v*)(Kg + (size_t)(j * 16 + fr) * HD + kc * 8);
    }

    // ---- QK^T (64x64, K=32): NT form, 16 MFMA ----
    f32x4 sc[4][4] = {};
#pragma unroll
    for (int i = 0; i < 4; ++i)
#pragma unroll
        for (int j = 0; j < 4; ++j)
            sc[i][j] = __builtin_amdgcn_mfma_f32_16x16x32_bf16(qa[i], kb[j], sc[i][j], 0, 0, 0);

    __syncthreads();   // Vt + bcol visible (single wave: cheap)

    // ---- scale + rel-pos bias + shift mask + row softmax ----
    const float scale = 0.17677669529663687f;   // 32^-0.5
    const int nwin = win & 255;
    const bool lastrow = ((nwin >> 4) == 15);
    const bool lastcol = ((nwin & 15) == 15);

    // hoisted per-lane j-side quantities
    int cj[4];
    bool jh4[4], jw4[4], jvalid[4];
#pragma unroll
    for (int tj = 0; tj < 4; ++tj) {
        const int j = tj * 16 + fr;
        const int jh = j / 7, jw = j - jh * 7;
        jvalid[tj] = (j < SW);
        cj[tj] = jh * 13 + jw;
        jh4[tj] = (jh < 4);
        jw4[tj] = (jw < 4);
    }

#pragma unroll
    for (int ti = 0; ti < 4; ++ti) {
#pragma unroll
        for (int v = 0; v < 4; ++v) {
            const int i = ti * 16 + kc * 4 + v;
            const int ih = i / 7, iw = i - ih * 7;
            const bool ivalid = (i < SW);
            const int ci = ih * 13 + iw;
            const bool ih4 = (ih < 4), iw4 = (iw < 4);
            float vals[4];
#pragma unroll
            for (int tj = 0; tj < 4; ++tj) {
                const bool ok = ivalid && jvalid[tj];
                const int bidx = ok ? (ci - cj[tj] + 84) : 0;  // clamp: no OOB LDS
                const float bv = bcol[bidx];
                const bool msk = (lastrow && (ih4 != jh4[tj])) ||
                                 (lastcol && (iw4 != jw4[tj]));
                const float s = sc[ti][tj][v] * scale + bv;
                vals[tj] = (ok && !msk) ? s : -1e30f;
            }
            float mx = fmaxf(fmaxf(vals[0], vals[1]), fmaxf(vals[2], vals[3]));
#pragma unroll
            for (int t = 1; t < 16; t <<= 1) mx = fmaxf(mx, __shfl_xor(mx, t));
            float e[4], sum = 0.0f;
#pragma unroll
            for (int tj = 0; tj < 4; ++tj) { e[tj] = __expf(vals[tj] - mx); sum += e[tj]; }
#pragma unroll
            for (int t = 1; t < 16; t <<= 1) sum += __shfl_xor(sum, t);
            const float inv = 1.0f / sum;
#pragma unroll
            for (int tj = 0; tj < 4; ++tj)
                Ps[i][tj * 16 + fr] = f2bf(e[tj] * inv);   // exact zeros for j>=49
        }
    }
    __syncthreads();

    // ---- PV (64x32, K=64): A=Ps rows, B=Vt rows (NT), 16 MFMA ----
    f32x4 oa[4][2] = {};
#pragma unroll
    for (int ks = 0; ks < 2; ++ks) {
        s8v pa[4], vb[2];
#pragma unroll
        for (int ti = 0; ti < 4; ++ti) pa[ti] = *(const s8v*)&Ps[ti * 16 + fr][ks * 32 + kc * 8];
#pragma unroll
        for (int tj = 0; tj < 2; ++tj) vb[tj] = *(const s8v*)&Vt[tj * 16 + fr][ks * 32 + kc * 8];
#pragma unroll
        for (int ti = 0; ti < 4; ++ti)
#pragma unroll
            for (int tj = 0; tj < 2; ++tj)
                oa[ti][tj] = __builtin_amdgcn_mfma_f32_16x16x32_bf16(pa[ti], vb[tj], oa[ti][tj], 0, 0, 0);
    }

    // ---- write out rows i<49 into (B,N,S,C) bf16 ----
#pragma unroll
    for (int ti = 0; ti < 4; ++ti)
#pragma unroll
        for (int tj = 0; tj < 2; ++tj)
#pragma unroll
            for (int v = 0; v < 4; ++v) {
                const int i = ti * 16 + kc * 4 + v;
                if (i < SW) {
                    const int d = tj * 16 + fr;
                    outp[((size_t)win * SW + i) * CDIM + head * HD + d] = f2bf(oa[ti][tj][v]);
                }
            }
}

// ---------------- host orchestration ----------------
extern "C" void kernel_launch(void* const* d_in, const int* in_sizes, int n_in,
                              void* d_out, int out_size, void* d_ws, size_t ws_size,
                              hipStream_t stream) {
    const float* x       = (const float*)d_in[0];
    // d_in[1] = reshape (int64) - unused, geometry is static
    const float* n1g     = (const float*)d_in[2];
    const float* n1b     = (const float*)d_in[3];
    const float* qkv_w   = (const float*)d_in[4];
    const float* qkv_b   = (const float*)d_in[5];
    const float* proj_w  = (const float*)d_in[6];
    const float* proj_b  = (const float*)d_in[7];
    const float* n2g     = (const float*)d_in[8];
    const float* n2b     = (const float*)d_in[9];
    const float* mlp_w1  = (const float*)d_in[10];
    const float* mlp_b1  = (const float*)d_in[11];
    const float* mlp_w2  = (const float*)d_in[12];
    const float* mlp_b2  = (const float*)d_in[13];
    const float* btab    = (const float*)d_in[14];

    const int R = R_TOTAL;

    // workspace layout (bytes); hid reuses qkv+attno (dead by then), h2 reuses h
    char* w = (char*)d_ws;
    unsigned short* wqkv  = (unsigned short*)w; w += (size_t)768 * 256 * 2;
    unsigned short* wproj = (unsigned short*)w; w += (size_t)256 * 256 * 2;
    unsigned short* wm1   = (unsigned short*)w; w += (size_t)1024 * 256 * 2;
    unsigned short* wm2   = (unsigned short*)w; w += (size_t)256 * 1024 * 2;
    unsigned short* hbuf  = (unsigned short*)w; w += (size_t)R * CDIM * 2;
    unsigned short* qkvb  = (unsigned short*)w;
    unsigned short* hid   = qkvb;               w += (size_t)3 * R * CDIM * 2;
    unsigned short* attno = (unsigned short*)w; w += (size_t)R * CDIM * 2;
    float*          x2    = (float*)w;          w += (size_t)R * CDIM * 4;
    unsigned short* h2    = hbuf;

    // weights -> bf16
    cvt_f32_bf16<<<192, 256, 0, stream>>>(qkv_w,  wqkv, 49152);
    cvt_f32_bf16<<<64,  256, 0, stream>>>(proj_w, wproj, 16384);
    cvt_f32_bf16<<<256, 256, 0, stream>>>(mlp_w1, wm1, 65536);
    cvt_f32_bf16<<<256, 256, 0, stream>>>(mlp_w2, wm2, 65536);

    // LN1 -> h (bf16)
    ln_rows<<<R / 4, 256, 0, stream>>>(x, n1g, n1b, hbuf, R);

    // QKV GEMM -> scattered qkv layout
    gemm_nt<0><<<784 * 6, 256, 0, stream>>>(hbuf, wqkv, qkv_b, nullptr, qkvb, R, 768, 256);

    // fused window attention
    attn_win<<<NWIN * NHEAD, 64, 0, stream>>>(qkvb, btab, attno);

    // proj GEMM + residual -> x2 (f32)
    gemm_nt<1><<<784 * 2, 256, 0, stream>>>(attno, wproj, proj_b, x, x2, R, 256, 256);

    // LN2 -> h2 (bf16)
    ln_rows<<<R / 4, 256, 0, stream>>>(x2, n2g, n2b, h2, R);

    // MLP1 + gelu -> hid (bf16)
    gemm_nt<2><<<784 * 8, 256, 0, stream>>>(h2, wm1, mlp_b1, nullptr, hid, R, 1024, 256);

    // MLP2 + residual -> d_out (f32)
    gemm_nt<3><<<784 * 2, 256, 0, stream>>>(hid, wm2, mlp_b2, x2, (float*)d_out, R, 256, 1024);
}